// Round 7
// baseline (85.598 us; speedup 1.0000x reference)
//
#include <hip/hip_runtime.h>

#define NG  512
#define GW  32768    // G*W
#define GH3 32768    // G*H3

typedef __attribute__((ext_vector_type(8))) short bf16x8;
typedef __attribute__((ext_vector_type(4))) float f32x4;
typedef __attribute__((ext_vector_type(4))) unsigned int u32x4;
typedef __attribute__((ext_vector_type(2))) __bf16 bf16x2;

union frag_u { u32x4 u; bf16x8 h; };

#define MFMA __builtin_amdgcn_mfma_f32_16x16x32_bf16

// two floats -> packed bf16 pair (RNE); clang fuses into v_cvt_pk_bf16_f32
__device__ __forceinline__ unsigned cvt2bf(float a, float b) {
  bf16x2 v = {(__bf16)a, (__bf16)b};
  return __builtin_bit_cast(unsigned, v);
}

// (E,O) packed D-words -> B-operand words via half/row swaps.
__device__ __forceinline__ void permswap(unsigned &e, unsigned &o) {
  asm volatile("s_nop 1\n\t"
               "v_permlane32_swap_b32 %0, %1\n\t"
               "s_nop 1\n\t"
               "v_permlane16_swap_b32 %0, %1\n\t"
               "s_nop 1"
               : "+v"(e), "+v"(o));
}

// One B-fragment from an acc-tile pair, with relu.
__device__ __forceinline__ void mk_bfrag1(f32x4 e, f32x4 o, frag_u &bf) {
  unsigned E0 = cvt2bf(fmaxf(e[0], 0.f), fmaxf(e[1], 0.f));
  unsigned E1 = cvt2bf(fmaxf(e[2], 0.f), fmaxf(e[3], 0.f));
  unsigned O0 = cvt2bf(fmaxf(o[0], 0.f), fmaxf(o[1], 0.f));
  unsigned O1 = cvt2bf(fmaxf(o[2], 0.f), fmaxf(o[3], 0.f));
  permswap(E0, O0);   // -> w0, w2
  permswap(E1, O1);   // -> w1, w3
  bf.u = (u32x4){E0, E1, O0, O1};
}

// Stage W[g] ([K][H] fp32 row-major) into LDS frag-major (conflict-free):
// frag (mt,kc) = 1024 contiguous bytes, lane slot at lane*16.
template<int K, int H>
__device__ __forceinline__ void stage_frag(const float* __restrict__ gsrc,
                                           char* ldsBase, int tid) {
  constexpr int KC = K / 32;
  constexpr int NELEM = (K / 8) * H;
  #pragma unroll
  for (int lin = tid; lin < NELEM; lin += 512) {
    const int h  = lin & (H - 1);
    const int kb = lin / H;
    const float* p = gsrc + h + (size_t)(8 * kb) * H;
    unsigned w0 = cvt2bf(p[0 * H], p[1 * H]);
    unsigned w1 = cvt2bf(p[2 * H], p[3 * H]);
    unsigned w2 = cvt2bf(p[4 * H], p[5 * H]);
    unsigned w3 = cvt2bf(p[6 * H], p[7 * H]);
    const int mt = h >> 4, bl = h & 15, kc = kb >> 2, bq = kb & 3;
    const int byteoff = ((mt * KC + kc) * 64 + bq * 16 + bl) * 16;
    *(u32x4*)(ldsBase + byteoff) = (u32x4){w0, w1, w2, w3};
  }
}

// Layer-1 B fragments straight from global (x^T layout is free).
__device__ __forceinline__ void ld_b1(const float* px, frag_u* b1) {
  #pragma unroll
  for (int kc = 0; kc < 2; ++kc) {
    f32x4 lo = *(const f32x4*)(px + 32 * kc);
    f32x4 hi = *(const f32x4*)(px + 32 * kc + 4);
    b1[kc].u = (u32x4){cvt2bf(lo[0], lo[1]), cvt2bf(lo[2], lo[3]),
                       cvt2bf(hi[0], hi[1]), cvt2bf(hi[2], hi[3])};
  }
}

__global__ __launch_bounds__(512, 4)
void DeepBlockDense_kernel(const float* __restrict__ x,
                           const float* __restrict__ w1,
                           const float* __restrict__ w2,
                           const float* __restrict__ w3,
                           float* __restrict__ out) {
  __shared__ __align__(16) char smem[65536];
  // T1 XCD-chunked swizzle (confirmed +15% r6): XCD k owns groups
  // [k*64,(k+1)*64) -> contiguous 16-KB span of every x/out row per XCD.
  const int g    = ((blockIdx.x & 7) << 6) + (blockIdx.x >> 3);
  const int tid  = threadIdx.x;
  const int lane = tid & 63;
  const int wid  = tid >> 6;
  const int bq   = lane >> 4;

  stage_frag<64 , 128>(w1 + (size_t)g * (64 * 128) , smem        , tid);
  stage_frag<128, 128>(w2 + (size_t)g * (128 * 128), smem + 16384, tid);
  stage_frag<128, 64 >(w3 + (size_t)g * (128 * 64) , smem + 49152, tid);
  __syncthreads();

  const char* aBase = smem + lane * 16;   // frags at compile-time imm offsets

  #pragma unroll 1
  for (int t = 0; t < 4; ++t) {
    const size_t r0 = (size_t)(t * 256 + wid * 16 + (lane & 15));
    const size_t r1 = r0 + 128;

    // ---- layer-1 B fragments for both batch tiles
    frag_u b1a[2], b1b[2];
    ld_b1(x + r0 * GW + g * 64 + 8 * bq, b1a);
    ld_b1(x + r1 * GW + g * 64 + 8 * bq, b1b);

    // ---- layer 1 (M=128,K=64), interleaved with b2-frag build per mt-pair
    frag_u b2a[4], b2b[4];
    #pragma unroll
    for (int pr = 0; pr < 4; ++pr) {
      f32x4 ea = {}, oa = {}, eb = {}, ob = {};
      #pragma unroll
      for (int kc = 0; kc < 2; ++kc) {
        frag_u ae, ao;
        ae.u = *(const u32x4*)(aBase + 1024 * ((2 * pr    ) * 2 + kc));
        ao.u = *(const u32x4*)(aBase + 1024 * ((2 * pr + 1) * 2 + kc));
        ea = MFMA(ae.h, b1a[kc].h, ea, 0, 0, 0);
        eb = MFMA(ae.h, b1b[kc].h, eb, 0, 0, 0);
        oa = MFMA(ao.h, b1a[kc].h, oa, 0, 0, 0);
        ob = MFMA(ao.h, b1b[kc].h, ob, 0, 0, 0);
      }
      mk_bfrag1(ea, oa, b2a[pr]);
      mk_bfrag1(eb, ob, b2b[pr]);
    }

    // ---- layer 2 (M=128,K=128) + layer 3 (M=64,K=128) interleaved per mt-pair
    f32x4 acc3a[4] = {}, acc3b[4] = {};
    #pragma unroll
    for (int pr = 0; pr < 4; ++pr) {
      f32x4 ea = {}, oa = {}, eb = {}, ob = {};
      #pragma unroll
      for (int kc = 0; kc < 4; ++kc) {
        frag_u ae, ao;
        ae.u = *(const u32x4*)(aBase + 16384 + 1024 * ((2 * pr    ) * 4 + kc));
        ao.u = *(const u32x4*)(aBase + 16384 + 1024 * ((2 * pr + 1) * 4 + kc));
        ea = MFMA(ae.h, b2a[kc].h, ea, 0, 0, 0);
        eb = MFMA(ae.h, b2b[kc].h, eb, 0, 0, 0);
        oa = MFMA(ao.h, b2a[kc].h, oa, 0, 0, 0);
        ob = MFMA(ao.h, b2b[kc].h, ob, 0, 0, 0);
      }
      frag_u b3a, b3b;
      mk_bfrag1(ea, oa, b3a);
      mk_bfrag1(eb, ob, b3b);
      #pragma unroll
      for (int mt = 0; mt < 4; ++mt) {
        frag_u a;
        a.u = *(const u32x4*)(aBase + 49152 + 1024 * (mt * 4 + pr));
        acc3a[mt] = MFMA(a.h, b3a.h, acc3a[mt], 0, 0, 0);
        acc3b[mt] = MFMA(a.h, b3b.h, acc3b[mt], 0, 0, 0);
      }
    }

    // ---- relu + plain cached stores (NT reverted: it inflated WRITE 131->184 MB)
    float* po0 = out + r0 * GH3 + g * 64 + 4 * bq;
    float* po1 = out + r1 * GH3 + g * 64 + 4 * bq;
    #pragma unroll
    for (int mt = 0; mt < 4; ++mt) {
      f32x4 va = acc3a[mt], vb = acc3b[mt];
      va[0] = fmaxf(va[0], 0.f); va[1] = fmaxf(va[1], 0.f);
      va[2] = fmaxf(va[2], 0.f); va[3] = fmaxf(va[3], 0.f);
      vb[0] = fmaxf(vb[0], 0.f); vb[1] = fmaxf(vb[1], 0.f);
      vb[2] = fmaxf(vb[2], 0.f); vb[3] = fmaxf(vb[3], 0.f);
      *(f32x4*)(po0 + 16 * mt) = va;
      *(f32x4*)(po1 + 16 * mt) = vb;
    }
  }
}

extern "C" void kernel_launch(void* const* d_in, const int* in_sizes, int n_in,
                              void* d_out, int out_size, void* d_ws, size_t ws_size,
                              hipStream_t stream) {
  const float* x  = (const float*)d_in[0];
  const float* w1 = (const float*)d_in[1];
  const float* w2 = (const float*)d_in[2];
  const float* w3 = (const float*)d_in[3];
  float* out = (float*)d_out;
  (void)in_sizes; (void)n_in; (void)out_size; (void)d_ws; (void)ws_size;
  DeepBlockDense_kernel<<<dim3(NG), dim3(512), 0, stream>>>(x, w1, w2, w3, out);
}

// Round 8
// 70.815 us; speedup vs baseline: 1.2087x; 1.2087x over previous
//
#include <hip/hip_runtime.h>

#define NG  512
#define GW  32768    // G*W
#define GH3 32768    // G*H3

typedef __attribute__((ext_vector_type(8))) short bf16x8;
typedef __attribute__((ext_vector_type(4))) float f32x4;
typedef __attribute__((ext_vector_type(4))) unsigned int u32x4;
typedef __attribute__((ext_vector_type(2))) __bf16 bf16x2;

union frag_u { u32x4 u; bf16x8 h; };

#define MFMA __builtin_amdgcn_mfma_f32_16x16x32_bf16

// two floats -> packed bf16 pair (RNE); clang fuses into v_cvt_pk_bf16_f32
__device__ __forceinline__ unsigned cvt2bf(float a, float b) {
  bf16x2 v = {(__bf16)a, (__bf16)b};
  return __builtin_bit_cast(unsigned, v);
}

// (E,O) packed D-words -> B-operand words via half/row swaps.
__device__ __forceinline__ void permswap(unsigned &e, unsigned &o) {
  asm volatile("s_nop 1\n\t"
               "v_permlane32_swap_b32 %0, %1\n\t"
               "s_nop 1\n\t"
               "v_permlane16_swap_b32 %0, %1\n\t"
               "s_nop 1"
               : "+v"(e), "+v"(o));
}

// One B-fragment from an acc-tile pair, with relu.
__device__ __forceinline__ void mk_bfrag1(f32x4 e, f32x4 o, frag_u &bf) {
  unsigned E0 = cvt2bf(fmaxf(e[0], 0.f), fmaxf(e[1], 0.f));
  unsigned E1 = cvt2bf(fmaxf(e[2], 0.f), fmaxf(e[3], 0.f));
  unsigned O0 = cvt2bf(fmaxf(o[0], 0.f), fmaxf(o[1], 0.f));
  unsigned O1 = cvt2bf(fmaxf(o[2], 0.f), fmaxf(o[3], 0.f));
  permswap(E0, O0);   // -> w0, w2
  permswap(E1, O1);   // -> w1, w3
  bf.u = (u32x4){E0, E1, O0, O1};
}

// Stage W[g] ([K][H] fp32 row-major) into LDS frag-major (conflict-free):
// frag (mt,kc) = 1024 contiguous bytes, lane slot at lane*16.
template<int K, int H>
__device__ __forceinline__ void stage_frag(const float* __restrict__ gsrc,
                                           char* ldsBase, int tid) {
  constexpr int KC = K / 32;
  constexpr int NELEM = (K / 8) * H;
  #pragma unroll
  for (int lin = tid; lin < NELEM; lin += 512) {
    const int h  = lin & (H - 1);
    const int kb = lin / H;
    const float* p = gsrc + h + (size_t)(8 * kb) * H;
    unsigned w0 = cvt2bf(p[0 * H], p[1 * H]);
    unsigned w1 = cvt2bf(p[2 * H], p[3 * H]);
    unsigned w2 = cvt2bf(p[4 * H], p[5 * H]);
    unsigned w3 = cvt2bf(p[6 * H], p[7 * H]);
    const int mt = h >> 4, bl = h & 15, kc = kb >> 2, bq = kb & 3;
    const int byteoff = ((mt * KC + kc) * 64 + bq * 16 + bl) * 16;
    *(u32x4*)(ldsBase + byteoff) = (u32x4){w0, w1, w2, w3};
  }
}

// Raw x row segment: 4 f32x4 (k-octets bq and bq+4).
__device__ __forceinline__ void ld_raw(const float* px, f32x4* d) {
  d[0] = *(const f32x4*)(px + 0);
  d[1] = *(const f32x4*)(px + 4);
  d[2] = *(const f32x4*)(px + 32);
  d[3] = *(const f32x4*)(px + 36);
}

__device__ __forceinline__ void cvt_b1(const f32x4* d, frag_u* b1) {
  b1[0].u = (u32x4){cvt2bf(d[0][0], d[0][1]), cvt2bf(d[0][2], d[0][3]),
                    cvt2bf(d[1][0], d[1][1]), cvt2bf(d[1][2], d[1][3])};
  b1[1].u = (u32x4){cvt2bf(d[2][0], d[2][1]), cvt2bf(d[2][2], d[2][3]),
                    cvt2bf(d[3][0], d[3][1]), cvt2bf(d[3][2], d[3][3])};
}

__global__ __launch_bounds__(512, 4)
void DeepBlockDense_kernel(const float* __restrict__ x,
                           const float* __restrict__ w1,
                           const float* __restrict__ w2,
                           const float* __restrict__ w3,
                           float* __restrict__ out) {
  __shared__ __align__(16) char smem[65536];
  // T1 XCD-chunked swizzle (co-present in r6's 72.4; free, kept).
  const int g    = ((blockIdx.x & 7) << 6) + (blockIdx.x >> 3);
  const int tid  = threadIdx.x;
  const int lane = tid & 63;
  const int wid  = tid >> 6;
  const int bq   = lane >> 4;

  const float* xbase = x + g * 64 + 8 * bq + (size_t)(wid * 16 + (lane & 15)) * GW;

  // T14: issue t=0 x-loads BEFORE staging (hide under stage phase)
  f32x4 xra[4], xrb[4];
  ld_raw(xbase + (size_t)0   * GW, xra);
  ld_raw(xbase + (size_t)128 * GW, xrb);

  stage_frag<64 , 128>(w1 + (size_t)g * (64 * 128) , smem        , tid);
  stage_frag<128, 128>(w2 + (size_t)g * (128 * 128), smem + 16384, tid);
  stage_frag<128, 64 >(w3 + (size_t)g * (128 * 64) , smem + 49152, tid);
  __syncthreads();

  const char* aBase = smem + lane * 16;   // frags at compile-time imm offsets

  #pragma unroll 1
  for (int t = 0; t < 4; ++t) {
    const size_t r0 = (size_t)(t * 256 + wid * 16 + (lane & 15));
    const size_t r1 = r0 + 128;

    // ---- consume prefetched x; immediately issue next iter's loads
    frag_u b1a[2], b1b[2];
    cvt_b1(xra, b1a);
    cvt_b1(xrb, b1b);
    if (t < 3) {
      ld_raw(xbase + (size_t)(t * 256 + 256) * GW, xra);
      ld_raw(xbase + (size_t)(t * 256 + 384) * GW, xrb);
    }

    // ---- layer 1 (M=128,K=64), interleaved with b2-frag build per mt-pair
    frag_u b2a[4], b2b[4];
    #pragma unroll
    for (int pr = 0; pr < 4; ++pr) {
      f32x4 ea = {}, oa = {}, eb = {}, ob = {};
      #pragma unroll
      for (int kc = 0; kc < 2; ++kc) {
        frag_u ae, ao;
        ae.u = *(const u32x4*)(aBase + 1024 * ((2 * pr    ) * 2 + kc));
        ao.u = *(const u32x4*)(aBase + 1024 * ((2 * pr + 1) * 2 + kc));
        ea = MFMA(ae.h, b1a[kc].h, ea, 0, 0, 0);
        eb = MFMA(ae.h, b1b[kc].h, eb, 0, 0, 0);
        oa = MFMA(ao.h, b1a[kc].h, oa, 0, 0, 0);
        ob = MFMA(ao.h, b1b[kc].h, ob, 0, 0, 0);
      }
      mk_bfrag1(ea, oa, b2a[pr]);
      mk_bfrag1(eb, ob, b2b[pr]);
    }

    // ---- layer 2 (M=128,K=128) + layer 3 (M=64,K=128) interleaved per mt-pair
    f32x4 acc3a[4] = {}, acc3b[4] = {};
    #pragma unroll
    for (int pr = 0; pr < 4; ++pr) {
      f32x4 ea = {}, oa = {}, eb = {}, ob = {};
      #pragma unroll
      for (int kc = 0; kc < 4; ++kc) {
        frag_u ae, ao;
        ae.u = *(const u32x4*)(aBase + 16384 + 1024 * ((2 * pr    ) * 4 + kc));
        ao.u = *(const u32x4*)(aBase + 16384 + 1024 * ((2 * pr + 1) * 4 + kc));
        ea = MFMA(ae.h, b2a[kc].h, ea, 0, 0, 0);
        eb = MFMA(ae.h, b2b[kc].h, eb, 0, 0, 0);
        oa = MFMA(ao.h, b2a[kc].h, oa, 0, 0, 0);
        ob = MFMA(ao.h, b2b[kc].h, ob, 0, 0, 0);
      }
      frag_u b3a, b3b;
      mk_bfrag1(ea, oa, b3a);
      mk_bfrag1(eb, ob, b3b);
      #pragma unroll
      for (int mt = 0; mt < 4; ++mt) {
        frag_u a;
        a.u = *(const u32x4*)(aBase + 49152 + 1024 * (mt * 4 + pr));
        acc3a[mt] = MFMA(a.h, b3a.h, acc3a[mt], 0, 0, 0);
        acc3b[mt] = MFMA(a.h, b3b.h, acc3b[mt], 0, 0, 0);
      }
    }

    // ---- relu + NT stores (r6: NT = -13us; L2 write-allocate relief).
    // All 4 va stores back-to-back = consecutive 64-B chunks per row
    // (+0,+64,+128,+192 B) to maximize NT write-combining runs.
    float* po0 = out + r0 * GH3 + g * 64 + 4 * bq;
    float* po1 = out + r1 * GH3 + g * 64 + 4 * bq;
    #pragma unroll
    for (int mt = 0; mt < 4; ++mt) {
      f32x4 va = acc3a[mt];
      va[0] = fmaxf(va[0], 0.f); va[1] = fmaxf(va[1], 0.f);
      va[2] = fmaxf(va[2], 0.f); va[3] = fmaxf(va[3], 0.f);
      __builtin_nontemporal_store(va, (f32x4*)(po0 + 16 * mt));
    }
    #pragma unroll
    for (int mt = 0; mt < 4; ++mt) {
      f32x4 vb = acc3b[mt];
      vb[0] = fmaxf(vb[0], 0.f); vb[1] = fmaxf(vb[1], 0.f);
      vb[2] = fmaxf(vb[2], 0.f); vb[3] = fmaxf(vb[3], 0.f);
      __builtin_nontemporal_store(vb, (f32x4*)(po1 + 16 * mt));
    }
  }
}

extern "C" void kernel_launch(void* const* d_in, const int* in_sizes, int n_in,
                              void* d_out, int out_size, void* d_ws, size_t ws_size,
                              hipStream_t stream) {
  const float* x  = (const float*)d_in[0];
  const float* w1 = (const float*)d_in[1];
  const float* w2 = (const float*)d_in[2];
  const float* w3 = (const float*)d_in[3];
  float* out = (float*)d_out;
  (void)in_sizes; (void)n_in; (void)out_size; (void)d_ws; (void)ws_size;
  DeepBlockDense_kernel<<<dim3(NG), dim3(512), 0, stream>>>(x, w1, w2, w3, out);
}